// Round 9
// baseline (163.198 us; speedup 1.0000x reference)
//
#include <hip/hip_runtime.h>

// MoE: out[b,:] = sum_e softmax(gate(x))[b,e] * (W3_e^T @ relu(W2_e^T @ relu(W1_e^T @ x_b + b1) + b2) + b3)
// R9: 32x32x16 MFMA redesign — 32 tokens/wave-tile. R7/R8 proved the kernel is VALU-bound at
//     13.4 VALU/token (pack stages dominate) and occupancy is pinned ~3 waves/SIMD regardless
//     of grid/attributes. 32x32 amortizes every per-tile cost over 2x tokens (~5.2 VALU/token).
//     Layout chaining: C/D row = (reg&3)+8*(reg>>2)+4h (HW-verified); next layer's A rows
//     pre-permuted by sigma_p(h,j)=(j&3)+8*((j>>2)+2p)+4h so C regs pack directly into B
//     operands in-lane. K=32 layers = two chained K=16 MFMAs. 2 experts/wave, 4-wave blocks.

typedef _Float16 half2_t __attribute__((ext_vector_type(2)));
typedef _Float16 half8_t __attribute__((ext_vector_type(8)));
typedef __fp16   fp16v2  __attribute__((ext_vector_type(2)));
typedef float  float2_t  __attribute__((ext_vector_type(2)));
typedef float  float16_t __attribute__((ext_vector_type(16)));
typedef int    int4_t    __attribute__((ext_vector_type(4)));

#define MFMA32(A, B, C) __builtin_amdgcn_mfma_f32_32x32x16_f16((A), (B), (C), 0, 0, 0)

static constexpr int E_ = 8, DIN_ = 6, H_ = 32, EPW_ = 2;

union H8U { half2_t h2[4]; half8_t h8; int4_t i4; };
union HI  { half2_t h; int i; };
union PKU { fp16v2 p; half2_t h; };

__device__ __forceinline__ half2_t pkrtz(float a, float b) {
    PKU u; u.p = __builtin_amdgcn_cvt_pkrtz(a, b);
    return u.h;
}

__device__ __forceinline__ half2_t relu2(half2_t v) {
    const half2_t z = {(_Float16)0.0f, (_Float16)0.0f};
    return __builtin_elementwise_max(v, z);
}

// sigma_p(h, j): input-channel carried by B-operand p, half h, k-slot j (= C/D row of reg p*8+j)
__device__ __forceinline__ int sigma(int p, int h, int j) {
    return (j & 3) + 8 * ((j >> 2) + 2 * p) + 4 * h;
}

__global__ __launch_bounds__(256)
void moe_kernel(
    const float* __restrict__ x,  const float* __restrict__ W1, const float* __restrict__ b1,
    const float* __restrict__ W2, const float* __restrict__ b2, const float* __restrict__ W3,
    const float* __restrict__ b3, const float* __restrict__ Wg1, const float* __restrict__ bg1,
    const float* __restrict__ Wg2, const float* __restrict__ bg2,
    float* __restrict__ out, int nTiles, int tilesPerBlock)
{
    const int tid  = threadIdx.x;
    const int lane = tid & 63;
    const int t32  = lane & 31;   // token (B col) == A row m
    const int h    = lane >> 5;   // half-wave (k-group)
    const int wv   = tid >> 6;    // wave in block: 0..3
    const int eb   = wv * EPW_;   // this wave's expert base

    __shared__ int      b2pk[128];          // [e][h][s]: f16 pairs of b2 in C-reg-pair order
    __shared__ float2_t cbuf[2][4][32];     // parity-double-buffered cross-wave partials

    const float L2E = 1.44269504f;

    if (tid < 128) {
        int e = tid >> 4, hh = (tid >> 3) & 1, s = tid & 7;
        int r0 = ((2 * s) & 3) + 8 * (s >> 1) + 4 * hh;   // row of C reg 2s
        HI u; u.h = pkrtz(b2[e * H_ + r0], b2[e * H_ + r0 + 1]);
        b2pk[tid] = u.i;
    }
    __syncthreads();

    const int m = t32;   // A-operand row for all weight fragments

    // ---- gate L1 A (K=16, k=h*8+j; h=0: 6 features + bias-as-1.0 + 0; h=1: 0)
    H8U G1;
    #pragma unroll
    for (int r = 0; r < 4; ++r) {
        int j0 = 2 * r, j1 = 2 * r + 1;
        float v0 = 0.f, v1 = 0.f;
        if (h == 0) {
            v0 = (j0 < DIN_) ? Wg1[j0 * H_ + m] : ((j0 == DIN_) ? bg1[m] : 0.f);
            v1 = (j1 < DIN_) ? Wg1[j1 * H_ + m] : ((j1 == DIN_) ? bg1[m] : 0.f);
        }
        G1.h2[r] = pkrtz(v0, v1);
    }
    // ---- gate L2 A (two K=16 parts, sigma-permuted rows), pre-scaled by log2(e)
    H8U Gg2[2];
    #pragma unroll
    for (int p = 0; p < 2; ++p)
        #pragma unroll
        for (int r = 0; r < 4; ++r) {
            int c0 = sigma(p, h, 2 * r);
            float v0 = (m < E_) ? Wg2[c0 * E_ + m] * L2E : 0.f;
            float v1 = (m < E_) ? Wg2[(c0 + 1) * E_ + m] * L2E : 0.f;
            Gg2[p].h2[r] = pkrtz(v0, v1);
        }

    // ---- this wave's 2 experts
    H8U A1[EPW_], A2[EPW_][2], A3[EPW_][2];
    #pragma unroll
    for (int jx = 0; jx < EPW_; ++jx) {
        const int e = eb + jx;
        #pragma unroll
        for (int r = 0; r < 4; ++r) {      // L1: natural k (h=0 only)
            int j0 = 2 * r, j1 = 2 * r + 1;
            float v0 = 0.f, v1 = 0.f;
            if (h == 0) {
                v0 = (j0 < DIN_) ? W1[(e * DIN_ + j0) * H_ + m] : ((j0 == DIN_) ? b1[e * H_ + m] : 0.f);
                v1 = (j1 < DIN_) ? W1[(e * DIN_ + j1) * H_ + m] : ((j1 == DIN_) ? b1[e * H_ + m] : 0.f);
            }
            A1[jx].h2[r] = pkrtz(v0, v1);
        }
        #pragma unroll
        for (int p = 0; p < 2; ++p)
            #pragma unroll
            for (int r = 0; r < 4; ++r) {  // L2: sigma-permuted input channels
                int c0 = sigma(p, h, 2 * r);
                A2[jx][p].h2[r] = pkrtz(W2[(e * H_ + c0) * H_ + m], W2[(e * H_ + c0 + 1) * H_ + m]);
            }
        const bool mine = (m >> 1) == e;   // output rows 2e, 2e+1 only
        const int  o    = m & 1;
        #pragma unroll
        for (int p = 0; p < 2; ++p)
            #pragma unroll
            for (int r = 0; r < 4; ++r) {  // L3: sigma-permuted, block-diagonal rows
                int c0 = sigma(p, h, 2 * r);
                float v0 = mine ? W3[(e * H_ + c0) * 2 + o] : 0.f;
                float v1 = mine ? W3[(e * H_ + c0 + 1) * 2 + o] : 0.f;
                A3[jx][p].h2[r] = pkrtz(v0, v1);
            }
    }

    // ---- per-lane consts: bg2 (log2 domain, rows r+4h), b3 shares (wave0 adds them)
    float bg2F[4], b3A[4], b3B[4];
    #pragma unroll
    for (int r = 0; r < 4; ++r) {
        bg2F[r] = bg2[r + 4 * h] * L2E;
        b3A[r]  = b3[4 * h + r];        // (e=2h+(r>>1), o=r&1)
        b3B[r]  = b3[8 + 4 * h + r];    // (e=4+2h+(r>>1), o=r&1)
    }
    const float16_t zero16 = {0.f,0.f,0.f,0.f, 0.f,0.f,0.f,0.f, 0.f,0.f,0.f,0.f, 0.f,0.f,0.f,0.f};

    const int tile0 = blockIdx.x * tilesPerBlock;

    const float* xq = x + ((size_t)tile0 * 32 + t32) * DIN_;
    float2_t la = {0.f, 0.f}, lb = {0.f, 0.f}, lc = {0.f, 0.f};
    if (tile0 < nTiles) {
        la = *(const float2_t*)(xq + 0);
        lb = *(const float2_t*)(xq + 2);
        lc = *(const float2_t*)(xq + 4);
    }
    HI one0; one0.h = pkrtz(1.f, 0.f);

    for (int it = 0; it < tilesPerBlock; ++it) {
        const int tile = tile0 + it;
        if (tile >= nTiles) break;          // uniform across the block

        // ---- x B-fragment: n=t32, k=h*8+j; h=0 slots = x0..x5,1,dc; h=1 = dc (A zero there)
        H8U ux;
        ux.h2[0] = pkrtz(la[0], la[1]);
        ux.h2[1] = pkrtz(lb[0], lb[1]);
        ux.h2[2] = pkrtz(lc[0], lc[1]);
        ux.h2[3] = one0.h;
        const half8_t xB = ux.h8;

        // ---- prefetch next tile's x
        if ((it + 1) < tilesPerBlock && (tile + 1) < nTiles) {
            const float* xn = xq + (size_t)(it + 1) * 32 * DIN_;
            la = *(const float2_t*)(xn + 0);
            lb = *(const float2_t*)(xn + 2);
            lc = *(const float2_t*)(xn + 4);
        }

        // ---- gate
        float16_t Cg = MFMA32(G1.h8, xB, zero16);
        H8U bg0, bg1v;
        #pragma unroll
        for (int r = 0; r < 4; ++r) {
            bg0.h2[r]  = relu2(pkrtz(Cg[2 * r], Cg[2 * r + 1]));
            bg1v.h2[r] = relu2(pkrtz(Cg[8 + 2 * r], Cg[9 + 2 * r]));
        }
        float16_t Cg2 = MFMA32(Gg2[0].h8, bg0.h8, zero16);
        Cg2 = MFMA32(Gg2[1].h8, bg1v.h8, Cg2);

        // ---- softmax over 8 experts (lane holds e = r+4h in Cg2[0..3]); norm deferred
        float ex0 = __builtin_amdgcn_exp2f(Cg2[0] + bg2F[0]);
        float ex1 = __builtin_amdgcn_exp2f(Cg2[1] + bg2F[1]);
        float ex2 = __builtin_amdgcn_exp2f(Cg2[2] + bg2F[2]);
        float ex3 = __builtin_amdgcn_exp2f(Cg2[3] + bg2F[3]);
        float s = (ex0 + ex1) + (ex2 + ex3);
        s += __shfl_xor(s, 32);
        float rs = __builtin_amdgcn_rcpf(s);
        HI pa, pb, xpa, xpb, eA, eB;
        pa.h = pkrtz(ex0, ex1);            // e = 4h, 4h+1
        pb.h = pkrtz(ex2, ex3);            // e = 4h+2, 4h+3
        xpa.i = __shfl_xor(pa.i, 32);
        xpb.i = __shfl_xor(pb.i, 32);
        eA.i = h ? xpb.i : pa.i;           // e pair (2h, 2h+1)   -> Y regs 0..3
        eB.i = h ? pb.i  : xpa.i;          // e pair (4+2h, 5+2h) -> Y regs 4..7
        float gA0 = (float)eA.h[0], gA1 = (float)eA.h[1];
        float gB0 = (float)eB.h[0], gB1 = (float)eB.h[1];

        // ---- experts: L1 -> pack -> L2(2 chained) -> +b2/pack -> L3(2 chained, shared Y)
        float16_t Y = zero16;
        #pragma unroll
        for (int jx = 0; jx < EPW_; ++jx) {
            float16_t C1 = MFMA32(A1[jx].h8, xB, zero16);
            H8U u0, u1;
            #pragma unroll
            for (int r = 0; r < 4; ++r) {
                u0.h2[r] = relu2(pkrtz(C1[2 * r], C1[2 * r + 1]));
                u1.h2[r] = relu2(pkrtz(C1[8 + 2 * r], C1[9 + 2 * r]));
            }
            float16_t C2 = MFMA32(A2[jx][0].h8, u0.h8, zero16);
            C2 = MFMA32(A2[jx][1].h8, u1.h8, C2);
            H8U ua, ub;
            const int base = (eb + jx) * 16 + h * 8;
            ua.i4 = *(const int4_t*)&b2pk[base];
            ub.i4 = *(const int4_t*)&b2pk[base + 4];
            H8U q0, q1;
            #pragma unroll
            for (int r = 0; r < 4; ++r) {
                q0.h2[r] = relu2(pkrtz(C2[2 * r], C2[2 * r + 1]) + ua.h2[r]);
                q1.h2[r] = relu2(pkrtz(C2[8 + 2 * r], C2[9 + 2 * r]) + ub.h2[r]);
            }
            Y = MFMA32(A3[jx][0].h8, q0.h8, Y);
            Y = MFMA32(A3[jx][1].h8, q1.h8, Y);
        }

        // ---- gated partial over this wave's experts (other Y rows are zero)
        float p0 = gA0 * Y[0] + gA1 * Y[2] + gB0 * Y[4] + gB1 * Y[6];
        float p1 = gA0 * Y[1] + gA1 * Y[3] + gB0 * Y[5] + gB1 * Y[7];
        if (wv == 0) {   // b3 term: sum_e g_e*b3[e][o], added once (wave0), both halves
            p0 += gA0 * b3A[0] + gA1 * b3A[2] + gB0 * b3B[0] + gB1 * b3B[2];
            p1 += gA0 * b3A[1] + gA1 * b3A[3] + gB0 * b3B[1] + gB1 * b3B[3];
        }
        p0 += __shfl_xor(p0, 32);
        p1 += __shfl_xor(p1, 32);

        // ---- cross-wave combine (parity double-buffer, one barrier per tile)
        if (lane < 32) {
            float2_t o = {p0, p1};
            cbuf[it & 1][wv][t32] = o;
        }
        __syncthreads();
        if (wv == 0 && lane < 32) {
            float2_t o  = cbuf[it & 1][0][t32];
            float2_t o1 = cbuf[it & 1][1][t32];
            float2_t o2 = cbuf[it & 1][2][t32];
            float2_t o3 = cbuf[it & 1][3][t32];
            o[0] = (o[0] + o1[0] + o2[0] + o3[0]) * rs;
            o[1] = (o[1] + o1[1] + o2[1] + o3[1]) * rs;
            *(float2_t*)(out + ((size_t)tile * 32 + t32) * 2) = o;
        }
    }
}

extern "C" void kernel_launch(void* const* d_in, const int* in_sizes, int n_in,
                              void* d_out, int out_size, void* d_ws, size_t ws_size,
                              hipStream_t stream) {
    const float* x   = (const float*)d_in[0];
    const float* W1  = (const float*)d_in[1];
    const float* b1  = (const float*)d_in[2];
    const float* W2  = (const float*)d_in[3];
    const float* b2  = (const float*)d_in[4];
    const float* W3  = (const float*)d_in[5];
    const float* b3  = (const float*)d_in[6];
    const float* Wg1 = (const float*)d_in[7];
    const float* bg1 = (const float*)d_in[8];
    const float* Wg2 = (const float*)d_in[9];
    const float* bg2 = (const float*)d_in[10];
    float* out = (float*)d_out;

    const int B      = in_sizes[0] / DIN_;
    const int nTiles = (B + 31) / 32;           // 32-token tiles
    const int blocks = 1024;
    const int tpb    = (nTiles + blocks - 1) / blocks;

    moe_kernel<<<blocks, 256, 0, stream>>>(x, W1, b1, W2, b2, W3, b3,
                                           Wg1, bg1, Wg2, bg2, out, nTiles, tpb);
}